// Round 1
// baseline (533.233 us; speedup 1.0000x reference)
//
#include <hip/hip_runtime.h>
#include <hip/hip_bf16.h>

// Problem dims (fixed by setup_inputs)
#define B_ 4
#define S_ 2048
#define D_ 1024
#define E_ 8
#define F_ 4096
#define C_ 512
#define BE_ (B_*E_)

typedef __attribute__((ext_vector_type(8))) short bf16x8;
typedef __attribute__((ext_vector_type(4))) float f32x4;
typedef unsigned short u16;

// ---------------- workspace layout (bytes) ----------------
// aff   (BE,S)   f32 : 262144
// idx   (BE,C)   i32 : 65536
// gate  (BE,C)   f32 : 65536
// x_in  (BE,C,D) bf16: 33554432
// wt1   (E,F,D)  bf16: 67108864   (w1 transposed per expert)
// wt2   (E,D,F)  bf16: 67108864   (w2 transposed per expert)
// h     (BE,C,F) bf16: 134217728
static constexpr size_t OFF_AFF  = 0;
static constexpr size_t OFF_IDX  = 262144;
static constexpr size_t OFF_GATE = 327680;
static constexpr size_t OFF_XIN  = 393216;
static constexpr size_t OFF_WT1  = OFF_XIN + (size_t)BE_*C_*D_*2;       // 33947648
static constexpr size_t OFF_WT2  = OFF_WT1 + (size_t)E_*F_*D_*2;        // 101056512
static constexpr size_t OFF_H    = OFF_WT2 + (size_t)E_*D_*F_*2;        // 168165376
static constexpr size_t WS_NEED  = OFF_H   + (size_t)BE_*C_*F_*2;       // ~288 MB

static __device__ __forceinline__ u16 f2bf(float x) {
  __hip_bfloat16 h = __float2bfloat16(x);
  return *reinterpret_cast<u16*>(&h);
}

static __device__ __forceinline__ void gload16(const void* g, void* l) {
  __builtin_amdgcn_global_load_lds(
      (const __attribute__((address_space(1))) unsigned int*)g,
      (__attribute__((address_space(3))) unsigned int*)l, 16, 0, 0);
}

// ---------------- 1. router logits + softmax -> aff (B,E,S) ----------------
__global__ void router_kernel(const float* __restrict__ x,
                              const float* __restrict__ router,
                              float* __restrict__ aff) {
  int t = blockIdx.x;            // token id b*S+s
  int b = t / S_, s = t % S_;
  int lane = threadIdx.x;        // 64 threads
  const float* xrow = x + (size_t)t * D_;
  float acc[E_];
#pragma unroll
  for (int e = 0; e < E_; ++e) acc[e] = 0.f;
  for (int i = 0; i < D_/64; ++i) {
    int d = lane + i*64;
    float xv = xrow[d];
    const float* r = router + (size_t)d * E_;
#pragma unroll
    for (int e = 0; e < E_; ++e) acc[e] += xv * r[e];
  }
#pragma unroll
  for (int e = 0; e < E_; ++e) {
    float v = acc[e];
    for (int off = 32; off; off >>= 1) v += __shfl_down(v, off);
    acc[e] = v;
  }
  if (lane == 0) {
    float mx = acc[0];
#pragma unroll
    for (int e = 1; e < E_; ++e) mx = fmaxf(mx, acc[e]);
    float ev[E_]; float sum = 0.f;
#pragma unroll
    for (int e = 0; e < E_; ++e) { ev[e] = expf(acc[e] - mx); sum += ev[e]; }
    float inv = 1.0f / sum;
#pragma unroll
    for (int e = 0; e < E_; ++e) aff[((size_t)(b*E_ + e))*S_ + s] = ev[e]*inv;
  }
}

// ---------------- 2. top-k (C of S) per (b,e): bitonic sort ----------------
__global__ void topk_kernel(const float* __restrict__ aff,
                            int* __restrict__ idxb, float* __restrict__ gateb) {
  __shared__ unsigned long long keys[S_];
  int be = blockIdx.x;
  const float* a = aff + (size_t)be * S_;
  int tid = threadIdx.x;         // 1024 threads
  for (int i = tid; i < S_; i += 1024) {
    unsigned vb = __float_as_uint(a[i]);   // affinities > 0
    keys[i] = ((unsigned long long)(~vb) << 32) | (unsigned)i;  // asc => val desc, idx asc
  }
  __syncthreads();
  for (int k = 2; k <= S_; k <<= 1) {
    for (int j = k >> 1; j > 0; j >>= 1) {
      for (int i = tid; i < S_; i += 1024) {
        int ixj = i ^ j;
        if (ixj > i) {
          unsigned long long ka = keys[i], kb = keys[ixj];
          bool up = ((i & k) == 0);
          if ((ka > kb) == up) { keys[i] = kb; keys[ixj] = ka; }
        }
      }
      __syncthreads();
    }
  }
  for (int c = tid; c < C_; c += 1024) {
    unsigned long long kk = keys[c];
    idxb[be*C_ + c]  = (int)(kk & 0xffffffffu);
    gateb[be*C_ + c] = __uint_as_float(~(unsigned)(kk >> 32));
  }
}

// ---------------- 3. gather x rows -> x_in (BE,C,D) bf16 ----------------
__global__ void gather_kernel(const float* __restrict__ x,
                              const int* __restrict__ idxb,
                              u16* __restrict__ x_in) {
  int rid = blockIdx.x;          // be*C + c
  int be = rid >> 9;             // /C_
  int b = be >> 3;               // /E_
  int tok = idxb[rid];
  const float4* src = (const float4*)(x + ((size_t)(b * S_ + tok)) * D_);
  ushort4* dst = (ushort4*)(x_in + (size_t)rid * D_);
  int t = threadIdx.x;           // 128 threads
#pragma unroll
  for (int i = 0; i < 2; ++i) {
    float4 v = src[t + i*128];
    ushort4 o;
    o.x = f2bf(v.x); o.y = f2bf(v.y); o.z = f2bf(v.z); o.w = f2bf(v.w);
    dst[t + i*128] = o;
  }
}

// ---------------- 4. transpose+convert weights: (E,RI,RJ) f32 -> (E,RJ,RI) bf16 ----
__global__ void trans_kernel(const float* __restrict__ src,
                             u16* __restrict__ dst, int RI, int RJ) {
  __shared__ float t[64][65];
  int e  = blockIdx.z;
  int j0 = blockIdx.x * 64;      // src col block
  int i0 = blockIdx.y * 64;      // src row block
  const float* s = src + (size_t)e * RI * RJ;
  u16* d = dst + (size_t)e * RI * RJ;
  int tid = threadIdx.x;         // 256
#pragma unroll
  for (int it = 0; it < 4; ++it) {
    int fid = it*256 + tid;
    int r = fid >> 4, c4 = fid & 15;
    float4 v = *(const float4*)(s + (size_t)(i0 + r) * RJ + j0 + c4*4);
    t[r][c4*4+0] = v.x; t[r][c4*4+1] = v.y; t[r][c4*4+2] = v.z; t[r][c4*4+3] = v.w;
  }
  __syncthreads();
#pragma unroll
  for (int it = 0; it < 4; ++it) {
    int fid = it*256 + tid;
    int rn = fid >> 4, c4 = fid & 15;   // output row rn (src col), k-quad c4
    ushort4 o;
    o.x = f2bf(t[c4*4+0][rn]); o.y = f2bf(t[c4*4+1][rn]);
    o.z = f2bf(t[c4*4+2][rn]); o.w = f2bf(t[c4*4+3][rn]);
    *(ushort4*)(d + (size_t)(j0 + rn) * RI + i0 + c4*4) = o;
  }
}

// ---------------- 5. grouped GEMM, m97 structure ----------------
// C[M=128 x N=128] per block; A (be,C_,K) row-major bf16; Bt (e,N,K) bf16 (pre-transposed).
// EPI 0: h = gelu(acc + b1), bf16 out.  EPI 1: atomic scatter (acc + b2) * gate -> dout.
template<int EPI, int N, int K>
__global__ __launch_bounds__(256, 2)
void gemm_kernel(const u16* __restrict__ A, const u16* __restrict__ Bt,
                 const float* __restrict__ bias, void* __restrict__ outp,
                 const int* __restrict__ idxb, const float* __restrict__ gateb,
                 float* __restrict__ dout) {
  __shared__ __align__(16) char lds[32768];   // A tile 16KB | B tile 16KB, [128][64] bf16 each
  char* ldsA = lds;
  char* ldsB = lds + 16384;
  const int tid  = threadIdx.x;
  const int wave = tid >> 6, lane = tid & 63;
  const int be = blockIdx.z;
  const int e  = be & (E_-1);
  const int m0 = blockIdx.y * 128;
  const int n0 = blockIdx.x * 128;
  const u16* Ab = A  + (size_t)be * C_ * K + (size_t)m0 * K;
  const u16* Bb = Bt + (size_t)e  * N  * K + (size_t)n0 * K;

  f32x4 acc[4][4];
#pragma unroll
  for (int i = 0; i < 4; ++i)
#pragma unroll
    for (int j = 0; j < 4; ++j) acc[i][j] = (f32x4){0.f,0.f,0.f,0.f};

  const int wr = wave >> 1, wc = wave & 1;
  const int chi = lane >> 4;    // 0..3
  const int l15 = lane & 15;

  for (int kt = 0; kt < K/64; ++kt) {
    const int k0 = kt * 64;
    // stage both tiles: [row 0..127][64 bf16] linear LDS, source col-chunk swizzled
#pragma unroll
    for (int i = 0; i < 4; ++i) {
      int slot = i*256 + tid;
      int row = slot >> 3, c = slot & 7;
      int sc = (c ^ (row & 7)) << 3;     // bf16 elements
      gload16(Ab + (size_t)row * K + k0 + sc, ldsA + (i*256 + wave*64)*16);
      gload16(Bb + (size_t)row * K + k0 + sc, ldsB + (i*256 + wave*64)*16);
    }
    __syncthreads();
    bf16x8 af[2][4], bfr[2][4];
#pragma unroll
    for (int kk = 0; kk < 2; ++kk) {
#pragma unroll
      for (int mi = 0; mi < 4; ++mi) {
        int row = wr*64 + mi*16 + l15;
        int ch  = kk*4 + chi;
        af[kk][mi] = *(const bf16x8*)(ldsA + row*128 + (((ch ^ (row & 7)) << 4)));
        int rowb = wc*64 + mi*16 + l15;
        bfr[kk][mi] = *(const bf16x8*)(ldsB + rowb*128 + (((ch ^ (rowb & 7)) << 4)));
      }
    }
#pragma unroll
    for (int kk = 0; kk < 2; ++kk)
#pragma unroll
      for (int mi = 0; mi < 4; ++mi)
#pragma unroll
        for (int ni = 0; ni < 4; ++ni)
          acc[mi][ni] = __builtin_amdgcn_mfma_f32_16x16x32_bf16(
              af[kk][mi], bfr[kk][ni], acc[mi][ni], 0, 0, 0);
    __syncthreads();
  }

  const int r4 = lane >> 4;
  if (EPI == 0) {
    __hip_bfloat16* hb = (__hip_bfloat16*)outp + (size_t)be * C_ * N;
    const float* bias_e = bias + e * N;
#pragma unroll
    for (int mi = 0; mi < 4; ++mi) {
#pragma unroll
      for (int j = 0; j < 4; ++j) {
        int row = m0 + wr*64 + mi*16 + r4*4 + j;
        __hip_bfloat16* hrow = hb + (size_t)row * N;
#pragma unroll
        for (int ni = 0; ni < 4; ++ni) {
          int col = n0 + wc*64 + ni*16 + l15;
          float v = acc[mi][ni][j] + bias_e[col];
          float g = 0.5f * v * (1.0f + erff(v * 0.70710678118654752f));
          hrow[col] = __float2bfloat16(g);
        }
      }
    }
  } else {
    const float* bias_e = bias + e * N;   // N == D_
    int b = be >> 3;
#pragma unroll
    for (int mi = 0; mi < 4; ++mi) {
#pragma unroll
      for (int j = 0; j < 4; ++j) {
        int rowl = m0 + wr*64 + mi*16 + r4*4 + j;
        int tok = idxb[be*C_ + rowl];
        float gt = gateb[be*C_ + rowl];
        float* orow = dout + ((size_t)b * S_ + tok) * (size_t)D_;
#pragma unroll
        for (int ni = 0; ni < 4; ++ni) {
          int col = n0 + wc*64 + ni*16 + l15;
          float v = (acc[mi][ni][j] + bias_e[col]) * gt;
          atomicAdd(orow + col, v);
        }
      }
    }
  }
}

extern "C" void kernel_launch(void* const* d_in, const int* in_sizes, int n_in,
                              void* d_out, int out_size, void* d_ws, size_t ws_size,
                              hipStream_t stream) {
  const float* x      = (const float*)d_in[0];
  const float* router = (const float*)d_in[1];
  const float* w1     = (const float*)d_in[2];
  const float* b1     = (const float*)d_in[3];
  const float* w2     = (const float*)d_in[4];
  const float* b2     = (const float*)d_in[5];
  float* out = (float*)d_out;

  if (ws_size < WS_NEED) return;   // workspace too small: fail visibly

  char* ws = (char*)d_ws;
  float* aff   = (float*)(ws + OFF_AFF);
  int*   idxb  = (int*)(ws + OFF_IDX);
  float* gateb = (float*)(ws + OFF_GATE);
  u16*   x_in  = (u16*)(ws + OFF_XIN);
  u16*   wt1   = (u16*)(ws + OFF_WT1);
  u16*   wt2   = (u16*)(ws + OFF_WT2);
  u16*   h     = (u16*)(ws + OFF_H);

  router_kernel<<<B_*S_, 64, 0, stream>>>(x, router, aff);
  topk_kernel<<<BE_, 1024, 0, stream>>>(aff, idxb, gateb);
  gather_kernel<<<BE_*C_, 128, 0, stream>>>(x, idxb, x_in);
  trans_kernel<<<dim3(F_/64, D_/64, E_), 256, 0, stream>>>(w1, wt1, D_, F_);
  trans_kernel<<<dim3(D_/64, F_/64, E_), 256, 0, stream>>>(w2, wt2, F_, D_);
  hipMemsetAsync(d_out, 0, (size_t)out_size * sizeof(float), stream);

  gemm_kernel<0, F_, D_><<<dim3(F_/128, C_/128, BE_), 256, 0, stream>>>(
      x_in, wt1, b1, (void*)h, nullptr, nullptr, nullptr);
  gemm_kernel<1, D_, F_><<<dim3(D_/128, C_/128, BE_), 256, 0, stream>>>(
      h, wt2, b2, nullptr, idxb, gateb, out);
}

// Round 2
// 483.937 us; speedup vs baseline: 1.1019x; 1.1019x over previous
//
#include <hip/hip_runtime.h>
#include <hip/hip_bf16.h>

// Problem dims (fixed by setup_inputs)
#define B_ 4
#define S_ 2048
#define D_ 1024
#define E_ 8
#define F_ 4096
#define C_ 512
#define BE_ (B_*E_)

typedef __attribute__((ext_vector_type(8))) short bf16x8;
typedef __attribute__((ext_vector_type(4))) float f32x4;
typedef unsigned short u16;

// ---------------- workspace layout (bytes) ----------------
static constexpr size_t OFF_AFF  = 0;
static constexpr size_t OFF_IDX  = 262144;
static constexpr size_t OFF_GATE = 327680;
static constexpr size_t OFF_XIN  = 393216;
static constexpr size_t OFF_WT1  = OFF_XIN + (size_t)BE_*C_*D_*2;       // 33947648
static constexpr size_t OFF_WT2  = OFF_WT1 + (size_t)E_*F_*D_*2;        // 101056512
static constexpr size_t OFF_H    = OFF_WT2 + (size_t)E_*D_*F_*2;        // 168165376
static constexpr size_t WS_NEED  = OFF_H   + (size_t)BE_*C_*F_*2;       // ~288 MB

static __device__ __forceinline__ u16 f2bf(float x) {
  __hip_bfloat16 h = __float2bfloat16(x);
  return *reinterpret_cast<u16*>(&h);
}

static __device__ __forceinline__ void gload16(const void* g, void* l) {
  __builtin_amdgcn_global_load_lds(
      (const __attribute__((address_space(1))) unsigned int*)g,
      (__attribute__((address_space(3))) unsigned int*)l, 16, 0, 0);
}

// ---------------- 1. router logits + softmax -> aff (B,E,S) ----------------
__global__ void router_kernel(const float* __restrict__ x,
                              const float* __restrict__ router,
                              float* __restrict__ aff) {
  int t = blockIdx.x;            // token id b*S+s
  int b = t / S_, s = t % S_;
  int lane = threadIdx.x;        // 64 threads
  const float* xrow = x + (size_t)t * D_;
  float acc[E_];
#pragma unroll
  for (int e = 0; e < E_; ++e) acc[e] = 0.f;
  for (int i = 0; i < D_/64; ++i) {
    int d = lane + i*64;
    float xv = xrow[d];
    const float* r = router + (size_t)d * E_;
#pragma unroll
    for (int e = 0; e < E_; ++e) acc[e] += xv * r[e];
  }
#pragma unroll
  for (int e = 0; e < E_; ++e) {
    float v = acc[e];
    for (int off = 32; off; off >>= 1) v += __shfl_down(v, off);
    acc[e] = v;
  }
  if (lane == 0) {
    float mx = acc[0];
#pragma unroll
    for (int e = 1; e < E_; ++e) mx = fmaxf(mx, acc[e]);
    float ev[E_]; float sum = 0.f;
#pragma unroll
    for (int e = 0; e < E_; ++e) { ev[e] = expf(acc[e] - mx); sum += ev[e]; }
    float inv = 1.0f / sum;
#pragma unroll
    for (int e = 0; e < E_; ++e) aff[((size_t)(b*E_ + e))*S_ + s] = ev[e]*inv;
  }
}

// ---------------- 2. top-k (C of S) per (b,e): bitonic sort ----------------
__global__ void topk_kernel(const float* __restrict__ aff,
                            int* __restrict__ idxb, float* __restrict__ gateb) {
  __shared__ unsigned long long keys[S_];
  int be = blockIdx.x;
  const float* a = aff + (size_t)be * S_;
  int tid = threadIdx.x;         // 1024 threads
  for (int i = tid; i < S_; i += 1024) {
    unsigned vb = __float_as_uint(a[i]);   // affinities > 0
    keys[i] = ((unsigned long long)(~vb) << 32) | (unsigned)i;  // asc => val desc, idx asc
  }
  __syncthreads();
  for (int k = 2; k <= S_; k <<= 1) {
    for (int j = k >> 1; j > 0; j >>= 1) {
      for (int i = tid; i < S_; i += 1024) {
        int ixj = i ^ j;
        if (ixj > i) {
          unsigned long long ka = keys[i], kb = keys[ixj];
          bool up = ((i & k) == 0);
          if ((ka > kb) == up) { keys[i] = kb; keys[ixj] = ka; }
        }
      }
      __syncthreads();
    }
  }
  for (int c = tid; c < C_; c += 1024) {
    unsigned long long kk = keys[c];
    idxb[be*C_ + c]  = (int)(kk & 0xffffffffu);
    gateb[be*C_ + c] = __uint_as_float(~(unsigned)(kk >> 32));
  }
}

// ---------------- 3. gather x rows -> x_in (BE,C,D) bf16 ----------------
__global__ void gather_kernel(const float* __restrict__ x,
                              const int* __restrict__ idxb,
                              u16* __restrict__ x_in) {
  int rid = blockIdx.x;          // be*C + c
  int be = rid >> 9;             // /C_
  int b = be >> 3;               // /E_
  int tok = idxb[rid];
  const float4* src = (const float4*)(x + ((size_t)(b * S_ + tok)) * D_);
  ushort4* dst = (ushort4*)(x_in + (size_t)rid * D_);
  int t = threadIdx.x;           // 128 threads
#pragma unroll
  for (int i = 0; i < 2; ++i) {
    float4 v = src[t + i*128];
    ushort4 o;
    o.x = f2bf(v.x); o.y = f2bf(v.y); o.z = f2bf(v.z); o.w = f2bf(v.w);
    dst[t + i*128] = o;
  }
}

// ---------------- 4. transpose+convert weights: (E,RI,RJ) f32 -> (E,RJ,RI) bf16 ----
__global__ void trans_kernel(const float* __restrict__ src,
                             u16* __restrict__ dst, int RI, int RJ) {
  __shared__ float t[64][65];
  int e  = blockIdx.z;
  int j0 = blockIdx.x * 64;      // src col block
  int i0 = blockIdx.y * 64;      // src row block
  const float* s = src + (size_t)e * RI * RJ;
  u16* d = dst + (size_t)e * RI * RJ;
  int tid = threadIdx.x;         // 256
#pragma unroll
  for (int it = 0; it < 4; ++it) {
    int fid = it*256 + tid;
    int r = fid >> 4, c4 = fid & 15;
    float4 v = *(const float4*)(s + (size_t)(i0 + r) * RJ + j0 + c4*4);
    t[r][c4*4+0] = v.x; t[r][c4*4+1] = v.y; t[r][c4*4+2] = v.z; t[r][c4*4+3] = v.w;
  }
  __syncthreads();
#pragma unroll
  for (int it = 0; it < 4; ++it) {
    int fid = it*256 + tid;
    int rn = fid >> 4, c4 = fid & 15;   // output row rn (src col), k-quad c4
    ushort4 o;
    o.x = f2bf(t[c4*4+0][rn]); o.y = f2bf(t[c4*4+1][rn]);
    o.z = f2bf(t[c4*4+2][rn]); o.w = f2bf(t[c4*4+3][rn]);
    *(ushort4*)(d + (size_t)(j0 + rn) * RI + i0 + c4*4) = o;
  }
}

// ---------------- 5. grouped GEMM, m97 structure, XCD-clustered by expert ----
// 1D grid, bid decode: xcd = bid&7 = expert e (hardware round-robins dispatch
// id across the 8 XCDs, so all blocks of expert e share one XCD and its L2);
// within XCD: n fastest (blocks sharing an A-panel co-resident), then m, then b.
// C[M=128 x N=128] per block; A (be,C_,K) row-major bf16; Bt (e,N,K) bf16.
// EPI 0: h = gelu(acc + b1), bf16 out.  EPI 1: atomic scatter (acc + b2)*gate.
template<int EPI, int N, int K, int NBLK>
__global__ __launch_bounds__(256, 4)
void gemm_kernel(const u16* __restrict__ A, const u16* __restrict__ Bt,
                 const float* __restrict__ bias, void* __restrict__ outp,
                 const int* __restrict__ idxb, const float* __restrict__ gateb,
                 float* __restrict__ dout) {
  __shared__ __align__(16) char lds[32768];   // A tile 16KB | B tile 16KB
  char* ldsA = lds;
  char* ldsB = lds + 16384;
  const int tid  = threadIdx.x;
  const int wave = tid >> 6, lane = tid & 63;

  const int bid = blockIdx.x;
  const int e   = bid & 7;           // XCD id == expert id
  const int r   = bid >> 3;
  const int nb  = r % NBLK;
  const int rm  = r / NBLK;
  const int mb  = rm & 3;            // C_/128 = 4
  const int b   = rm >> 2;           // B_ = 4
  const int be  = b * E_ + e;
  const int m0  = mb * 128;
  const int n0  = nb * 128;

  const u16* Ab = A  + (size_t)be * C_ * K + (size_t)m0 * K;
  const u16* Bb = Bt + (size_t)e  * N  * K + (size_t)n0 * K;

  f32x4 acc[4][4];
#pragma unroll
  for (int i = 0; i < 4; ++i)
#pragma unroll
    for (int j = 0; j < 4; ++j) acc[i][j] = (f32x4){0.f,0.f,0.f,0.f};

  const int wr = wave >> 1, wc = wave & 1;
  const int chi = lane >> 4;    // 0..3
  const int l15 = lane & 15;

  for (int kt = 0; kt < K/64; ++kt) {
    const int k0 = kt * 64;
#pragma unroll
    for (int i = 0; i < 4; ++i) {
      int slot = i*256 + tid;
      int row = slot >> 3, c = slot & 7;
      int sc = (c ^ (row & 7)) << 3;     // bf16 elements
      gload16(Ab + (size_t)row * K + k0 + sc, ldsA + (i*256 + wave*64)*16);
      gload16(Bb + (size_t)row * K + k0 + sc, ldsB + (i*256 + wave*64)*16);
    }
    __syncthreads();
    bf16x8 af[2][4], bfr[2][4];
#pragma unroll
    for (int kk = 0; kk < 2; ++kk) {
#pragma unroll
      for (int mi = 0; mi < 4; ++mi) {
        int row = wr*64 + mi*16 + l15;
        int ch  = kk*4 + chi;
        af[kk][mi] = *(const bf16x8*)(ldsA + row*128 + (((ch ^ (row & 7)) << 4)));
        int rowb = wc*64 + mi*16 + l15;
        bfr[kk][mi] = *(const bf16x8*)(ldsB + rowb*128 + (((ch ^ (rowb & 7)) << 4)));
      }
    }
#pragma unroll
    for (int kk = 0; kk < 2; ++kk)
#pragma unroll
      for (int mi = 0; mi < 4; ++mi)
#pragma unroll
        for (int ni = 0; ni < 4; ++ni)
          acc[mi][ni] = __builtin_amdgcn_mfma_f32_16x16x32_bf16(
              af[kk][mi], bfr[kk][ni], acc[mi][ni], 0, 0, 0);
    __syncthreads();
  }

  const int r4 = lane >> 4;
  if (EPI == 0) {
    __hip_bfloat16* hb = (__hip_bfloat16*)outp + (size_t)be * C_ * N;
    const float* bias_e = bias + e * N;
#pragma unroll
    for (int mi = 0; mi < 4; ++mi) {
#pragma unroll
      for (int j = 0; j < 4; ++j) {
        int row = m0 + wr*64 + mi*16 + r4*4 + j;
        __hip_bfloat16* hrow = hb + (size_t)row * N;
#pragma unroll
        for (int ni = 0; ni < 4; ++ni) {
          int col = n0 + wc*64 + ni*16 + l15;
          float v = acc[mi][ni][j] + bias_e[col];
          float g = 0.5f * v * (1.0f + erff(v * 0.70710678118654752f));
          hrow[col] = __float2bfloat16(g);
        }
      }
    }
  } else {
    const float* bias_e = bias + e * N;   // N == D_
    int bb = be >> 3;
#pragma unroll
    for (int mi = 0; mi < 4; ++mi) {
#pragma unroll
      for (int j = 0; j < 4; ++j) {
        int rowl = m0 + wr*64 + mi*16 + r4*4 + j;
        int tok = idxb[be*C_ + rowl];
        float gt = gateb[be*C_ + rowl];
        float* orow = dout + ((size_t)bb * S_ + tok) * (size_t)D_;
#pragma unroll
        for (int ni = 0; ni < 4; ++ni) {
          int col = n0 + wc*64 + ni*16 + l15;
          float v = (acc[mi][ni][j] + bias_e[col]) * gt;
          atomicAdd(orow + col, v);
        }
      }
    }
  }
}

extern "C" void kernel_launch(void* const* d_in, const int* in_sizes, int n_in,
                              void* d_out, int out_size, void* d_ws, size_t ws_size,
                              hipStream_t stream) {
  const float* x      = (const float*)d_in[0];
  const float* router = (const float*)d_in[1];
  const float* w1     = (const float*)d_in[2];
  const float* b1     = (const float*)d_in[3];
  const float* w2     = (const float*)d_in[4];
  const float* b2     = (const float*)d_in[5];
  float* out = (float*)d_out;

  if (ws_size < WS_NEED) return;   // workspace too small: fail visibly

  char* ws = (char*)d_ws;
  float* aff   = (float*)(ws + OFF_AFF);
  int*   idxb  = (int*)(ws + OFF_IDX);
  float* gateb = (float*)(ws + OFF_GATE);
  u16*   x_in  = (u16*)(ws + OFF_XIN);
  u16*   wt1   = (u16*)(ws + OFF_WT1);
  u16*   wt2   = (u16*)(ws + OFF_WT2);
  u16*   h     = (u16*)(ws + OFF_H);

  router_kernel<<<B_*S_, 64, 0, stream>>>(x, router, aff);
  topk_kernel<<<BE_, 1024, 0, stream>>>(aff, idxb, gateb);
  gather_kernel<<<BE_*C_, 128, 0, stream>>>(x, idxb, x_in);
  trans_kernel<<<dim3(F_/64, D_/64, E_), 256, 0, stream>>>(w1, wt1, D_, F_);
  trans_kernel<<<dim3(D_/64, F_/64, E_), 256, 0, stream>>>(w2, wt2, F_, D_);
  hipMemsetAsync(d_out, 0, (size_t)out_size * sizeof(float), stream);

  // GEMM1: (BE)x(C x F) = x_in @ wt1^T ; grid = 8 * NBLK(32) * 4 * 4 = 4096
  gemm_kernel<0, F_, D_, F_/128><<<E_*(F_/128)*4*B_, 256, 0, stream>>>(
      x_in, wt1, b1, (void*)h, nullptr, nullptr, nullptr);
  // GEMM2: (BE)x(C x D) = h @ wt2^T ; grid = 8 * NBLK(8) * 4 * 4 = 1024
  gemm_kernel<1, D_, F_, D_/128><<<E_*(D_/128)*4*B_, 256, 0, stream>>>(
      h, wt2, b2, nullptr, idxb, gateb, out);
}